// Round 3
// baseline (1830.840 us; speedup 1.0000x reference)
//
#include <hip/hip_runtime.h>
#include <stdint.h>

#define H_   16
#define DK_  128
#define DV_  128
#define HID_ 2048
#define KS_  4
#define B_   4
#define T_   2048
#define BT_  (B_*T_)     // 8192
#define QKVC (3*HID_)    // 6144

typedef unsigned short u16;
typedef short  bf16x8 __attribute__((ext_vector_type(8)));
typedef u16    u16x8  __attribute__((ext_vector_type(8)));
typedef u16    u16x4  __attribute__((ext_vector_type(4)));
typedef float  f32x4  __attribute__((ext_vector_type(4)));
typedef float  f32x2  __attribute__((ext_vector_type(2)));

__device__ __forceinline__ float b2f(u16 u){
  union { unsigned int i; float f; } v; v.i = ((unsigned int)u) << 16; return v.f;
}
__device__ __forceinline__ u16 f2b(float f){
  unsigned int x = __float_as_uint(f);
  unsigned int r = (x + 0x7FFFu + ((x >> 16) & 1u)) >> 16;
  return (u16)r;
}
__device__ __forceinline__ float sigm(float x){ return 1.0f / (1.0f + __expf(-x)); }

// ---------------- x conversion: f32 (bf16-valued) -> bf16, vectorized ----------------
__global__ __launch_bounds__(256) void cvt_x_k(const f32x4* __restrict__ src,
                                               u16x4* __restrict__ dst, int n4)
{
  int i0 = blockIdx.x * 256 + threadIdx.x;
  int stride = gridDim.x * 256;
  for (int i = i0; i < n4; i += stride) {
    f32x4 v = src[i];
    u16x4 r; r[0] = f2b(v[0]); r[1] = f2b(v[1]); r[2] = f2b(v[2]); r[3] = f2b(v[3]);
    dst[i] = r;
  }
}

// ---------------- small-tensor conversions, one launch ----------------
// canon layout: [0,24576) conv weights q|k|v (each 2048*4), [24576,30720) conv biases,
// [30720,30752) ba|bb, [30752,31008) lnw|lnb
__global__ __launch_bounds__(256) void cvt_small_k(
    const float* __restrict__ qcw, const float* __restrict__ kcw, const float* __restrict__ vcw,
    const float* __restrict__ qcb, const float* __restrict__ kcb, const float* __restrict__ vcb,
    const float* __restrict__ ba,  const float* __restrict__ bb,
    const float* __restrict__ lnw, const float* __restrict__ lnb,
    u16* __restrict__ canon)
{
  int i = blockIdx.x * 256 + threadIdx.x;
  if (i >= 31008) return;
  float v;
  if (i < 24576) {
    const float* s = (i < 8192) ? qcw : (i < 16384) ? kcw : vcw;
    v = s[i & 8191];
  } else if (i < 30720) {
    int j = i - 24576;
    const float* s = (j < 2048) ? qcb : (j < 4096) ? kcb : vcb;
    v = s[j & 2047];
  } else if (i < 30752) {
    int j = i - 30720;
    v = (j < 16) ? ba[j] : bb[j - 16];
  } else {
    int j = i - 30752;
    v = (j < 128) ? lnw[j] : lnb[j - 128];
  }
  canon[i] = f2b(v);
}

// ---------------- batched transpose: src_z[R][C] f32 -> dst + z*R*C, [C][R] bf16 ----------------
__global__ __launch_bounds__(256) void transpose_b(const float* __restrict__ s0,
                                                   const float* __restrict__ s1,
                                                   const float* __restrict__ s2,
                                                   u16* __restrict__ dst,
                                                   int R, int C)
{
  int z = blockIdx.z;
  const float* src = (z == 0) ? s0 : (z == 1) ? s1 : s2;
  u16* d = dst + (size_t)z * R * C;
  __shared__ u16 t[32][33];
  int bx = blockIdx.x * 32;
  int by = blockIdx.y * 32;
  int lx = threadIdx.x & 31, ly = threadIdx.x >> 5;
  #pragma unroll
  for (int i = 0; i < 4; ++i) {
    int r = by + ly + i * 8, c = bx + lx;
    if (r < R && c < C) t[ly + i * 8][lx] = f2b(src[(size_t)r * C + c]);
  }
  __syncthreads();
  #pragma unroll
  for (int i = 0; i < 4; ++i) {
    int r = bx + ly + i * 8;
    int c = by + lx;
    if (r < C && c < R) d[(size_t)r * R + c] = t[lx][ly + i * 8];
  }
}

// ---------------- m97-style bf16 GEMM: C[M,N] = A[M,K] * BT[N,K]^T ----------------
#define BM 128
#define BN 128
#define BK 32

__device__ __forceinline__ void gload_lds16(const void* gp, void* lp){
  __builtin_amdgcn_global_load_lds(
      (const __attribute__((address_space(1))) void*)gp,
      (__attribute__((address_space(3))) void*)lp, 16, 0, 0);
}

__global__ __launch_bounds__(256) void gemm_bt(const u16* __restrict__ A, int lda,
                                               const u16* __restrict__ Bt, int ldb,
                                               void* __restrict__ C, int ldc,
                                               int K, int out_f32)
{
  __shared__ u16 lsA[BM * BK];
  __shared__ u16 lsB[BN * BK];
  int tid = threadIdx.x, wave = tid >> 6, lane = tid & 63;
  int m0 = blockIdx.y * BM, n0 = blockIdx.x * BN;
  int wm = (wave >> 1) * 64, wn = (wave & 1) * 64;
  int srow = lane >> 2;
  int skel = (lane & 3) * 8;
  int quad = lane >> 4, l16 = lane & 15;

  f32x4 acc[4][4];
  #pragma unroll
  for (int mi = 0; mi < 4; ++mi)
    #pragma unroll
    for (int ni = 0; ni < 4; ++ni)
      #pragma unroll
      for (int r = 0; r < 4; ++r) acc[mi][ni][r] = 0.0f;

  for (int k0 = 0; k0 < K; k0 += BK) {
    __syncthreads();
    #pragma unroll
    for (int i = 0; i < 2; ++i) {
      int row = wave * 32 + i * 16 + srow;
      gload_lds16(A  + (size_t)(m0 + row) * lda + k0 + skel,
                  lsA + (wave * 2048 + i * 1024) / 2);
      gload_lds16(Bt + (size_t)(n0 + row) * ldb + k0 + skel,
                  lsB + (wave * 2048 + i * 1024) / 2);
    }
    __syncthreads();

    const bf16x8* fA = (const bf16x8*)lsA;
    const bf16x8* fB = (const bf16x8*)lsB;
    bf16x8 af[4], bg[4];
    #pragma unroll
    for (int mi = 0; mi < 4; ++mi) af[mi] = fA[(wm + mi * 16 + l16) * 4 + quad];
    #pragma unroll
    for (int ni = 0; ni < 4; ++ni) bg[ni] = fB[(wn + ni * 16 + l16) * 4 + quad];
    #pragma unroll
    for (int mi = 0; mi < 4; ++mi)
      #pragma unroll
      for (int ni = 0; ni < 4; ++ni)
        acc[mi][ni] = __builtin_amdgcn_mfma_f32_16x16x32_bf16(af[mi], bg[ni], acc[mi][ni], 0, 0, 0);
  }

  #pragma unroll
  for (int mi = 0; mi < 4; ++mi)
    #pragma unroll
    for (int ni = 0; ni < 4; ++ni)
      #pragma unroll
      for (int r = 0; r < 4; ++r) {
        int m = m0 + wm + mi * 16 + quad * 4 + r;
        int n = n0 + wn + ni * 16 + l16;
        if (out_f32) ((float*)C)[(size_t)m * ldc + n] = acc[mi][ni][r];
        else         ((u16*)C)[(size_t)m * ldc + n] = f2b(acc[mi][ni][r]);
      }
}

// ---------------- alpha/beta: sigmoid(x @ Wab + bias) ----------------
__global__ __launch_bounds__(256) void ab_k(const u16* __restrict__ x,
                                            const u16* __restrict__ WabT,
                                            const u16* __restrict__ ba,
                                            const u16* __restrict__ bb,
                                            float* __restrict__ ab)
{
  int j = threadIdx.x & 31, rl = threadIdx.x >> 5;
  int row = blockIdx.x * 8 + rl;
  const u16x8* xr = (const u16x8*)(x + (size_t)row * HID_);
  const u16x8* wr = (const u16x8*)(WabT + (size_t)j * HID_);
  float acc = 0.f;
  for (int k = 0; k < HID_ / 8; ++k) {
    u16x8 xv = xr[k], wv = wr[k];
    #pragma unroll
    for (int i = 0; i < 8; ++i) acc += b2f(xv[i]) * b2f(wv[i]);
  }
  float bias = (j < 16) ? b2f(ba[j]) : b2f(bb[j - 16]);
  float sg = sigm(acc + bias);
  if (j < 16) ab[(size_t)row * 16 + j] = sg;
  else        ab[(size_t)BT_ * 16 + (size_t)row * 16 + (j - 16)] = sg;
}

// ---------------- causal dwconv (KS=4) + silu (+ k scale); one batch chunk ----------------
__global__ __launch_bounds__(256) void conv_silu_k(const u16* __restrict__ in,   // [T_][QKVC]
                                                   const u16* __restrict__ cwv,  // [3*2048][4]
                                                   const u16* __restrict__ cbv,  // [3*2048]
                                                   u16* __restrict__ out)
{
  int idx  = blockIdx.x * 256 + threadIdx.x;
  int col8 = idx % (QKVC / 8);
  int t    = idx / (QKVC / 8);
  int col  = col8 * 8;
  int s = col >> 11;          // 0:q 1:k 2:v

  u16 wl[32];
  #pragma unroll
  for (int i = 0; i < 4; ++i)
    *(u16x8*)(wl + i * 8) = *(const u16x8*)(cwv + (size_t)col * KS_ + i * 8);
  u16x8 bv = *(const u16x8*)(cbv + col);

  float acc[8];
  #pragma unroll
  for (int j = 0; j < 8; ++j) acc[j] = b2f(bv[j]);

  #pragma unroll
  for (int tap = 0; tap < KS_; ++tap) {
    int tt = t - 3 + tap;
    if (tt >= 0) {
      u16x8 xv = *(const u16x8*)(in + (size_t)tt * QKVC + col);
      #pragma unroll
      for (int j = 0; j < 8; ++j) acc[j] = fmaf(b2f(xv[j]), b2f(wl[j * 4 + tap]), acc[j]);
    }
  }
  float scale = (s == 1) ? 0.08838834764831845f : 1.0f;   // DK^-0.5 folded into k
  u16x8 rv;
  #pragma unroll
  for (int j = 0; j < 8; ++j) {
    float a = acc[j];
    rv[j] = f2b(a * sigm(a) * scale);
  }
  *(u16x8*)(out + (size_t)t * QKVC + col) = rv;
}

// ---------------- sequential gated delta-rule scan ----------------
// R3: packed-f32 math. R2 left the scan ISSUE-bound (VALUBusy 72%, 650 busy cy/step).
// CDNA4 has full-rate v_pk_{mul,fma}_f32; holding state/k/q as float2 pairs halves
// the core VALU stream (dot 11->5, update 16->8, out-dot 11->5 instrs). Everything
// else (8-deep ring, XCD-pinned chains, DPP-only 16-lane reduce) unchanged.
// grid: 512 blocks = 64 (b,h) chains x 8 row-chunks; 256 threads = 16 rows x 16 lanes.
__device__ __forceinline__ float row16_allsum(float s){
  int t;
  t = __builtin_amdgcn_update_dpp(0, __float_as_int(s), 0xB1, 0xf, 0xf, true);  // quad_perm [1,0,3,2] (xor 1)
  s += __int_as_float(t);
  t = __builtin_amdgcn_update_dpp(0, __float_as_int(s), 0x4E, 0xf, 0xf, true);  // quad_perm [2,3,0,1] (xor 2)
  s += __int_as_float(t);
  t = __builtin_amdgcn_update_dpp(0, __float_as_int(s), 0x124, 0xf, 0xf, true); // row_ror:4
  s += __int_as_float(t);
  t = __builtin_amdgcn_update_dpp(0, __float_as_int(s), 0x128, 0xf, 0xf, true); // row_ror:8
  s += __int_as_float(t);
  return s;   // all 16 lanes of each DPP row hold the full sum
}

// one dword of 2 packed bf16 -> float2 (elem0 = low half)
__device__ __forceinline__ f32x2 up2(unsigned int d){
  f32x2 r;
  r.x = __uint_as_float(d << 16);
  r.y = __uint_as_float(d & 0xffff0000u);
  return r;
}

#define PF_ 8   // prefetch ring depth

__global__ __launch_bounds__(256) void scan_k(const u16* __restrict__ qkv,     // [BT_][QKVC] bf16
                                              const float* __restrict__ ab,    // [2][BT_][16] f32
                                              u16* __restrict__ o)             // [BT_][2048] bf16
{
  int chain = blockIdx.x & 63, rc = blockIdx.x >> 6;   // rc in [0,8)
  int b = chain >> 4, h = chain & 15;
  int w = threadIdx.x >> 6, lane = threadIdx.x & 63;
  int c = lane & 15, rg = lane >> 4;                   // c: k-slice, rg: row within wave
  int vr = rc * 16 + w * 4 + rg;                       // v-row in [0,128)
  const u16* base = qkv + (size_t)b * T_ * QKVC;
  int qofs = h * DK_ + c * 8;
  int kofs = HID_ + qofs;
  int vofs = 2 * HID_ + h * DV_ + vr;
  const float* abase = ab + (size_t)b * T_ * 16 + h;
  const float* bbase = abase + (size_t)BT_ * 16;
  u16* obase = o + (size_t)b * T_ * 2048 + h * DV_ + vr;

  f32x2 S0 = {0.f, 0.f}, S1 = {0.f, 0.f}, S2 = {0.f, 0.f}, S3 = {0.f, 0.f};

  u16x8 kraw[PF_], qraw[PF_];
  u16   vraw[PF_];
  float ga[PF_], gb[PF_];
  #pragma unroll
  for (int p = 0; p < PF_; ++p) {
    const u16* rp = base + (size_t)p * QKVC;
    kraw[p] = *(const u16x8*)(rp + kofs);
    qraw[p] = *(const u16x8*)(rp + qofs);
    vraw[p] = rp[vofs];
    ga[p] = abase[(size_t)p * 16];
    gb[p] = bbase[(size_t)p * 16];
  }

#define SCAN_STEP(CUR, TT)                                                    \
  {                                                                           \
    union { u16x8 v; unsigned int d[4]; } ku, qu;                             \
    ku.v = kraw[CUR]; qu.v = qraw[CUR];                                       \
    f32x2 k0 = up2(ku.d[0]), k1 = up2(ku.d[1]);                               \
    f32x2 k2 = up2(ku.d[2]), k3 = up2(ku.d[3]);                               \
    f32x2 q0 = up2(qu.d[0]), q1 = up2(qu.d[1]);                               \
    f32x2 q2 = up2(qu.d[2]), q3 = up2(qu.d[3]);                               \
    float vv = b2f(vraw[CUR]);                                                \
    f32x2 dacc = k0 * S0;                                                     \
    dacc = k1 * S1 + dacc;                                                    \
    dacc = k2 * S2 + dacc;                                                    \
    dacc = k3 * S3 + dacc;                                                    \
    float dot = dacc.x + dacc.y;                                              \
    dot = row16_allsum(dot);                                                  \
    float at = ga[CUR];                                                       \
    float nbe = gb[CUR] * (vv - dot);      /* -b*err */                       \
    f32x2 at2 = {at, at};                                                     \
    f32x2 nb2 = {nbe, nbe};                                                   \
    S0 = nb2 * k0 + at2 * S0;                                                 \
    S1 = nb2 * k1 + at2 * S1;                                                 \
    S2 = nb2 * k2 + at2 * S2;                                                 \
    S3 = nb2 * k3 + at2 * S3;                                                 \
    f32x2 oacc = q0 * S0;                                                     \
    oacc = q1 * S1 + oacc;                                                    \
    oacc = q2 * S2 + oacc;                                                    \
    oacc = q3 * S3 + oacc;                                                    \
    float od = oacc.x + oacc.y;                                               \
    od = row16_allsum(od);                                                    \
    if (c == 0) obase[(size_t)(TT) * 2048] = f2b(od);                         \
    if ((TT) + PF_ < T_) {                                                    \
      const u16* rp = base + (size_t)((TT) + PF_) * QKVC;                     \
      kraw[CUR] = *(const u16x8*)(rp + kofs);                                 \
      qraw[CUR] = *(const u16x8*)(rp + qofs);                                 \
      vraw[CUR] = rp[vofs];                                                   \
      ga[CUR] = abase[(size_t)((TT) + PF_) * 16];                             \
      gb[CUR] = bbase[(size_t)((TT) + PF_) * 16];                             \
    }                                                                         \
  }

  for (int t = 0; t < T_; t += PF_) {
    SCAN_STEP(0, t)
    SCAN_STEP(1, t + 1)
    SCAN_STEP(2, t + 2)
    SCAN_STEP(3, t + 3)
    SCAN_STEP(4, t + 4)
    SCAN_STEP(5, t + 5)
    SCAN_STEP(6, t + 6)
    SCAN_STEP(7, t + 7)
  }
#undef SCAN_STEP
}

// ---------------- LayerNorm(DV) * sigmoid(g) ----------------
__global__ __launch_bounds__(256) void ln_gate_k(const u16* __restrict__ o_raw,
                                                 const u16* __restrict__ g,
                                                 const u16* __restrict__ lnw,
                                                 const u16* __restrict__ lnb,
                                                 u16* __restrict__ o_ln)
{
  int gid = blockIdx.x * 4 + (threadIdx.x >> 6);
  int lane = threadIdx.x & 63;
  int row = gid >> 4, h = gid & 15;
  size_t ofs = (size_t)row * 2048 + h * 128 + lane * 2;
  unsigned int e2 = *(const unsigned int*)(o_raw + ofs);
  float ex = b2f((u16)(e2 & 0xffff)), ey = b2f((u16)(e2 >> 16));
  float s = ex + ey, ss = ex * ex + ey * ey;
  #pragma unroll
  for (int m = 1; m < 64; m <<= 1) { s += __shfl_xor(s, m); ss += __shfl_xor(ss, m); }
  float mean = s * (1.f / 128.f);
  float var  = ss * (1.f / 128.f) - mean * mean;
  float rstd = rsqrtf(fmaxf(var, 0.f) + 1e-5f);
  float w0 = b2f(lnw[lane * 2]), w1 = b2f(lnw[lane * 2 + 1]);
  float b0 = b2f(lnb[lane * 2]), b1 = b2f(lnb[lane * 2 + 1]);
  unsigned int g2 = *(const unsigned int*)(g + ofs);
  float g0 = sigm(b2f((u16)(g2 & 0xffff))), g1 = sigm(b2f((u16)(g2 >> 16)));
  float r0 = ((ex - mean) * rstd * w0 + b0) * g0;
  float r1 = ((ey - mean) * rstd * w1 + b1) * g1;
  *(unsigned int*)(o_ln + ofs) = (unsigned int)f2b(r0) | ((unsigned int)f2b(r1) << 16);
}

// ---------------- host launch ----------------
extern "C" void kernel_launch(void* const* d_in, const int* in_sizes, int n_in,
                              void* d_out, int out_size, void* d_ws, size_t ws_size,
                              hipStream_t stream)
{
  const float* x   = (const float*)d_in[0];
  const float* Wq  = (const float*)d_in[1];
  const float* Wk  = (const float*)d_in[2];
  const float* Wv  = (const float*)d_in[3];
  const float* Wa  = (const float*)d_in[4];
  const float* ba  = (const float*)d_in[5];
  const float* Wb  = (const float*)d_in[6];
  const float* bb  = (const float*)d_in[7];
  const float* Wg  = (const float*)d_in[8];
  const float* Wo  = (const float*)d_in[9];
  const float* qcw = (const float*)d_in[10];
  const float* qcb = (const float*)d_in[11];
  const float* kcw = (const float*)d_in[12];
  const float* kcb = (const float*)d_in[13];
  const float* vcw = (const float*)d_in[14];
  const float* vcb = (const float*)d_in[15];
  const float* lnw = (const float*)d_in[16];
  const float* lnb = (const float*)d_in[17];
  (void)in_sizes; (void)n_in; (void)out_size;

  char* ws = (char*)d_ws;
  size_t off = 0;
  auto alloc = [&](size_t bytes) -> void* {
    void* p = ws + off; off += (bytes + 255) & ~(size_t)255; return p;
  };
  u16* WT    = (u16*)alloc((size_t)3 * HID_ * HID_ * 2);   // WTqkv; later WTg (+0), WTo (+HID_*HID_)
  u16* WabT  = (u16*)alloc((size_t)32 * HID_ * 2);
  u16* xc    = (u16*)alloc((size_t)BT_ * HID_ * 2);        // canonical bf16 x
  u16* canon = (u16*)alloc((size_t)31008 * 2);
  u16* preC  = (u16*)alloc((size_t)BT_ * HID_ * 2 * 2);    // pre-conv chunk / o_raw
  u16* post  = (u16*)alloc((size_t)BT_ * QKVC * 2);        // qkv post-conv; later g_raw / o_ln
  float* abuf = (float*)alloc((size_t)2 * BT_ * 16 * 4);
  if (off > ws_size) return;   // guard: ws too small -> clean absmax failure

  u16* cw_c  = canon;
  u16* cb_c  = canon + 24576;
  u16* ba_c  = canon + 30720;
  u16* bb_c  = canon + 30736;
  u16* lnw_c = canon + 30752;
  u16* lnb_c = canon + 30880;

  u16* o_raw = preC;
  u16* g_raw = post;
  u16* o_ln  = post + (size_t)BT_ * HID_;
  u16* WTg   = WT;   // overlays qkv weights after they're consumed

  dim3 tb(256);

  // 1) conversions (inputs are f32 arrays holding bf16-rounded values -> exact)
  cvt_x_k<<<dim3(4096), tb, 0, stream>>>((const f32x4*)x, (u16x4*)xc, BT_ * HID_ / 4);
  cvt_small_k<<<dim3(122), tb, 0, stream>>>(qcw, kcw, vcw, qcb, kcb, vcb, ba, bb, lnw, lnb, canon);

  // 2) weight transposes (batched over z)
  transpose_b<<<dim3(64, 64, 3), tb, 0, stream>>>(Wq, Wk, Wv, WT, HID_, HID_);
  transpose_b<<<dim3(1, 64, 2), tb, 0, stream>>>(Wa, Wb, Wb, WabT, HID_, 16);

  // 3) per-batch: fused q|k|v projection then causal conv+silu
  for (int b = 0; b < B_; ++b) {
    const u16* xb = xc + (size_t)b * T_ * HID_;
    gemm_bt<<<dim3(QKVC / BN, T_ / BM), tb, 0, stream>>>(xb, HID_, WT, HID_, preC, QKVC, HID_, 0);
    conv_silu_k<<<dim3(T_ * (QKVC / 8) / 256), tb, 0, stream>>>(
        preC, cw_c, cb_c, post + (size_t)b * T_ * QKVC);
  }

  // 4) g/o weight transposes into the (now free) WT region
  transpose_b<<<dim3(64, 64, 2), tb, 0, stream>>>(Wg, Wo, Wo, WTg, HID_, HID_);

  // 5) alpha/beta
  ab_k<<<dim3(BT_ / 8), tb, 0, stream>>>(xc, WabT, ba_c, bb_c, abuf);

  // 6) sequential scan (512 blocks = 64 chains x 8 chunks, XCD-local per chain)
  scan_k<<<dim3(512), tb, 0, stream>>>(post, abuf, o_raw);

  // 7) g projection (raw, pre-sigmoid)
  gemm_bt<<<dim3(HID_ / BN, BT_ / BM), tb, 0, stream>>>(xc, HID_, WTg, HID_, g_raw, HID_, HID_, 0);

  // 8) LN + gate
  ln_gate_k<<<dim3(BT_ * H_ / 4), tb, 0, stream>>>(o_raw, g_raw, lnw_c, lnb_c, o_ln);

  // 9) output projection -> d_out (f32)
  gemm_bt<<<dim3(HID_ / BN, BT_ / BM), tb, 0, stream>>>(o_ln, HID_,
      WT + (size_t)HID_ * HID_, HID_, d_out, HID_, HID_, 1);
}

// Round 4
// 1386.854 us; speedup vs baseline: 1.3201x; 1.3201x over previous
//
#include <hip/hip_runtime.h>
#include <stdint.h>

#define H_   16
#define DK_  128
#define DV_  128
#define HID_ 2048
#define KS_  4
#define B_   4
#define T_   2048
#define BT_  (B_*T_)     // 8192
#define QKVC (3*HID_)    // 6144
#define C_   32          // scan chunk length
#define RS_  32          // state rows per block

typedef unsigned short u16;
typedef short  bf16x8 __attribute__((ext_vector_type(8)));
typedef u16    u16x8  __attribute__((ext_vector_type(8)));
typedef u16    u16x4  __attribute__((ext_vector_type(4)));
typedef float  f32x4  __attribute__((ext_vector_type(4)));

__device__ __forceinline__ float b2f(u16 u){
  union { unsigned int i; float f; } v; v.i = ((unsigned int)u) << 16; return v.f;
}
__device__ __forceinline__ u16 f2b(float f){
  unsigned int x = __float_as_uint(f);
  unsigned int r = (x + 0x7FFFu + ((x >> 16) & 1u)) >> 16;
  return (u16)r;
}
__device__ __forceinline__ float sigm(float x){ return 1.0f / (1.0f + __expf(-x)); }

#define MFMA16(a,b,c) __builtin_amdgcn_mfma_f32_16x16x32_bf16((a),(b),(c),0,0,0)

// ---------------- x conversion: f32 (bf16-valued) -> bf16, vectorized ----------------
__global__ __launch_bounds__(256) void cvt_x_k(const f32x4* __restrict__ src,
                                               u16x4* __restrict__ dst, int n4)
{
  int i0 = blockIdx.x * 256 + threadIdx.x;
  int stride = gridDim.x * 256;
  for (int i = i0; i < n4; i += stride) {
    f32x4 v = src[i];
    u16x4 r; r[0] = f2b(v[0]); r[1] = f2b(v[1]); r[2] = f2b(v[2]); r[3] = f2b(v[3]);
    dst[i] = r;
  }
}

// ---------------- small-tensor conversions ----------------
__global__ __launch_bounds__(256) void cvt_small_k(
    const float* __restrict__ qcw, const float* __restrict__ kcw, const float* __restrict__ vcw,
    const float* __restrict__ qcb, const float* __restrict__ kcb, const float* __restrict__ vcb,
    const float* __restrict__ ba,  const float* __restrict__ bb,
    const float* __restrict__ lnw, const float* __restrict__ lnb,
    u16* __restrict__ canon)
{
  int i = blockIdx.x * 256 + threadIdx.x;
  if (i >= 31008) return;
  float v;
  if (i < 24576) {
    const float* s = (i < 8192) ? qcw : (i < 16384) ? kcw : vcw;
    v = s[i & 8191];
  } else if (i < 30720) {
    int j = i - 24576;
    const float* s = (j < 2048) ? qcb : (j < 4096) ? kcb : vcb;
    v = s[j & 2047];
  } else if (i < 30752) {
    int j = i - 30720;
    v = (j < 16) ? ba[j] : bb[j - 16];
  } else {
    int j = i - 30752;
    v = (j < 128) ? lnw[j] : lnb[j - 128];
  }
  canon[i] = f2b(v);
}

// ---------------- batched transpose ----------------
__global__ __launch_bounds__(256) void transpose_b(const float* __restrict__ s0,
                                                   const float* __restrict__ s1,
                                                   const float* __restrict__ s2,
                                                   u16* __restrict__ dst,
                                                   int R, int C)
{
  int z = blockIdx.z;
  const float* src = (z == 0) ? s0 : (z == 1) ? s1 : s2;
  u16* d = dst + (size_t)z * R * C;
  __shared__ u16 t[32][33];
  int bx = blockIdx.x * 32;
  int by = blockIdx.y * 32;
  int lx = threadIdx.x & 31, ly = threadIdx.x >> 5;
  #pragma unroll
  for (int i = 0; i < 4; ++i) {
    int r = by + ly + i * 8, c = bx + lx;
    if (r < R && c < C) t[ly + i * 8][lx] = f2b(src[(size_t)r * C + c]);
  }
  __syncthreads();
  #pragma unroll
  for (int i = 0; i < 4; ++i) {
    int r = bx + ly + i * 8;
    int c = by + lx;
    if (r < C && c < R) d[(size_t)r * R + c] = t[lx][ly + i * 8];
  }
}

// ---------------- m97-style bf16 GEMM ----------------
#define BM 128
#define BN 128
#define BK 32

__device__ __forceinline__ void gload_lds16(const void* gp, void* lp){
  __builtin_amdgcn_global_load_lds(
      (const __attribute__((address_space(1))) void*)gp,
      (__attribute__((address_space(3))) void*)lp, 16, 0, 0);
}

__global__ __launch_bounds__(256) void gemm_bt(const u16* __restrict__ A, int lda,
                                               const u16* __restrict__ Bt, int ldb,
                                               void* __restrict__ C, int ldc,
                                               int K, int out_f32)
{
  __shared__ u16 lsA[BM * BK];
  __shared__ u16 lsB[BN * BK];
  int tid = threadIdx.x, wave = tid >> 6, lane = tid & 63;
  int m0 = blockIdx.y * BM, n0 = blockIdx.x * BN;
  int wm = (wave >> 1) * 64, wn = (wave & 1) * 64;
  int srow = lane >> 2;
  int skel = (lane & 3) * 8;
  int quad = lane >> 4, l16 = lane & 15;

  f32x4 acc[4][4];
  #pragma unroll
  for (int mi = 0; mi < 4; ++mi)
    #pragma unroll
    for (int ni = 0; ni < 4; ++ni)
      #pragma unroll
      for (int r = 0; r < 4; ++r) acc[mi][ni][r] = 0.0f;

  for (int k0 = 0; k0 < K; k0 += BK) {
    __syncthreads();
    #pragma unroll
    for (int i = 0; i < 2; ++i) {
      int row = wave * 32 + i * 16 + srow;
      gload_lds16(A  + (size_t)(m0 + row) * lda + k0 + skel,
                  lsA + (wave * 2048 + i * 1024) / 2);
      gload_lds16(Bt + (size_t)(n0 + row) * ldb + k0 + skel,
                  lsB + (wave * 2048 + i * 1024) / 2);
    }
    __syncthreads();

    const bf16x8* fA = (const bf16x8*)lsA;
    const bf16x8* fB = (const bf16x8*)lsB;
    bf16x8 af[4], bg[4];
    #pragma unroll
    for (int mi = 0; mi < 4; ++mi) af[mi] = fA[(wm + mi * 16 + l16) * 4 + quad];
    #pragma unroll
    for (int ni = 0; ni < 4; ++ni) bg[ni] = fB[(wn + ni * 16 + l16) * 4 + quad];
    #pragma unroll
    for (int mi = 0; mi < 4; ++mi)
      #pragma unroll
      for (int ni = 0; ni < 4; ++ni)
        acc[mi][ni] = MFMA16(af[mi], bg[ni], acc[mi][ni]);
  }

  #pragma unroll
  for (int mi = 0; mi < 4; ++mi)
    #pragma unroll
    for (int ni = 0; ni < 4; ++ni)
      #pragma unroll
      for (int r = 0; r < 4; ++r) {
        int m = m0 + wm + mi * 16 + quad * 4 + r;
        int n = n0 + wn + ni * 16 + l16;
        if (out_f32) ((float*)C)[(size_t)m * ldc + n] = acc[mi][ni][r];
        else         ((u16*)C)[(size_t)m * ldc + n] = f2b(acc[mi][ni][r]);
      }
}

// ---------------- alpha/beta ----------------
__global__ __launch_bounds__(256) void ab_k(const u16* __restrict__ x,
                                            const u16* __restrict__ WabT,
                                            const u16* __restrict__ ba,
                                            const u16* __restrict__ bb,
                                            float* __restrict__ ab)
{
  int j = threadIdx.x & 31, rl = threadIdx.x >> 5;
  int row = blockIdx.x * 8 + rl;
  const u16x8* xr = (const u16x8*)(x + (size_t)row * HID_);
  const u16x8* wr = (const u16x8*)(WabT + (size_t)j * HID_);
  float acc = 0.f;
  for (int k = 0; k < HID_ / 8; ++k) {
    u16x8 xv = xr[k], wv = wr[k];
    #pragma unroll
    for (int i = 0; i < 8; ++i) acc += b2f(xv[i]) * b2f(wv[i]);
  }
  float bias = (j < 16) ? b2f(ba[j]) : b2f(bb[j - 16]);
  float sg = sigm(acc + bias);
  if (j < 16) ab[(size_t)row * 16 + j] = sg;
  else        ab[(size_t)BT_ * 16 + (size_t)row * 16 + (j - 16)] = sg;
}

// ---------------- causal dwconv (KS=4) + silu ----------------
__global__ __launch_bounds__(256) void conv_silu_k(const u16* __restrict__ in,
                                                   const u16* __restrict__ cwv,
                                                   const u16* __restrict__ cbv,
                                                   u16* __restrict__ out)
{
  int idx  = blockIdx.x * 256 + threadIdx.x;
  int col8 = idx % (QKVC / 8);
  int t    = idx / (QKVC / 8);
  int col  = col8 * 8;
  int s = col >> 11;

  u16 wl[32];
  #pragma unroll
  for (int i = 0; i < 4; ++i)
    *(u16x8*)(wl + i * 8) = *(const u16x8*)(cwv + (size_t)col * KS_ + i * 8);
  u16x8 bv = *(const u16x8*)(cbv + col);

  float acc[8];
  #pragma unroll
  for (int j = 0; j < 8; ++j) acc[j] = b2f(bv[j]);

  #pragma unroll
  for (int tap = 0; tap < KS_; ++tap) {
    int tt = t - 3 + tap;
    if (tt >= 0) {
      u16x8 xv = *(const u16x8*)(in + (size_t)tt * QKVC + col);
      #pragma unroll
      for (int j = 0; j < 8; ++j) acc[j] = fmaf(b2f(xv[j]), b2f(wl[j * 4 + tap]), acc[j]);
    }
  }
  float scale = (s == 1) ? 0.08838834764831845f : 1.0f;
  u16x8 rv;
  #pragma unroll
  for (int j = 0; j < 8; ++j) {
    float a = acc[j];
    rv[j] = f2b(a * sigm(a) * scale);
  }
  *(u16x8*)(out + (size_t)t * QKVC + col) = rv;
}

// ---------------- chunked gated delta-rule scan (UT transform, MFMA) ----------------
// Per (b,h): S_t = a_t S_{t-1} - u_t k_t^T, u_t = b_t(S_{t-1}k_t - v_t), o_t = S_t q_t.
// Chunk C=32, local cumulative P_t = prod a.  With SK0[t]=S0.k_t, KK[t,i]=k_i.k_t,
// KQ[t,i]=k_i.q_t, ubar_i = u_i/P_i, s_t = b_t P_{t-1}:
//   u_t = s_t SK0[t] - b_t v_t - s_t Sum_{i<t} KK[t,i] ubar_i        (triangular solve)
//   o_t = P_t SQ0[t] - Sum_{i<=t} (P_t/P_i) KQ[t,i] u_i              (MFMA)
//   S'  = P31 S0 - Sum_i (P31/P_i) u_i k_i^T                         (MFMA)
// Verified by hand on a C=2 scalar case against the reference step.
// Grid: 256 blocks = 4 row-slices x 64 chains (chain = bid&63 so a chain's 4 slices
// share bid%8 -> same XCD). 256 threads = 4 waves. State lives in MFMA accumulators.
// S,u,G enter MFMA as bf16 hi+lo pairs (Dekker) to keep f32-level accuracy.
__global__ __launch_bounds__(256) void chunk_scan_k(const u16* __restrict__ qkv,
                                                    const float* __restrict__ ab,
                                                    u16* __restrict__ o)
{
  __shared__ __align__(16) char smem[64000];
  u16 (*Kim)[136]  = (u16(*)[136])(smem);            // [32][136]  0..8704
  u16 (*Qim)[136]  = (u16(*)[136])(smem + 8704);     // 8704..17408 (U overlays after ph2)
  u16 (*Sh)[136]   = (u16(*)[136])(smem + 17408);    // 17408..26112 (images overlay after ph2)
  u16 (*Sl)[136]   = (u16(*)[136])(smem + 26112);    // 26112..34816
  u16 (*KT)[40]    = (u16(*)[40])(smem + 34816);     // [128][40] 34816..45056
  u16 (*Vim)[32]   = (u16(*)[32])(smem + 45056);     // [32][32]  45056..47104
  float (*KK)[32]  = (float(*)[32])(smem + 47104);   // f32 [32][32]
  float (*KQ)[32]  = (float(*)[32])(smem + 51200);
  float (*SK0)[32] = (float(*)[32])(smem + 55296);
  float (*SQ0)[32] = (float(*)[32])(smem + 59392);
  float (*PL4)[4]  = (float(*)[4])(smem + 63488);    // per-t {s_t, b_t, 1/P_t, P_t}
  float (*U)[32]   = (float(*)[32])(smem + 8704);    // overlays Qim
  u16 (*Gh)[40]  = (u16(*)[40])(smem + 17408);       // images overlay Sh/Sl
  u16 (*Gl)[40]  = (u16(*)[40])(smem + 19968);
  u16 (*Uch)[40] = (u16(*)[40])(smem + 22528);
  u16 (*Ucl)[40] = (u16(*)[40])(smem + 25088);
  u16 (*Uth)[40] = (u16(*)[40])(smem + 27648);
  u16 (*Utl)[40] = (u16(*)[40])(smem + 30208);

  int bid = blockIdx.x;
  int chain = bid & 63, rblk = bid >> 6;
  int b = chain >> 4, h = chain & 15;
  int tid = threadIdx.x, wv = tid >> 6, lane = tid & 63;
  int l16 = lane & 15, quad = lane >> 4;

  const u16* kbase = qkv + (size_t)b * T_ * QKVC + HID_ + h * DK_;
  const u16* qbase = qkv + (size_t)b * T_ * QKVC + h * DK_;
  const u16* vbase = qkv + (size_t)b * T_ * QKVC + 2 * HID_ + h * DV_ + rblk * RS_;
  const float* abase = ab + (size_t)b * T_ * 16 + h;
  const float* bbase = abase + (size_t)BT_ * 16;
  u16* obase = o + (size_t)b * T_ * 2048 + h * DV_ + rblk * RS_;

  // persistent state: wave wv owns cols [wv*32, wv*32+32)
  f32x4 st[2][2];
  #pragma unroll
  for (int rt = 0; rt < 2; ++rt)
    #pragma unroll
    for (int ct = 0; ct < 2; ++ct)
      #pragma unroll
      for (int r = 0; r < 4; ++r) st[rt][ct][r] = 0.f;

  for (int c = 0; c < T_ / C_; ++c) {
    int t0 = c * C_;

    // ---- ph1: state image + staging + gates ----
    #pragma unroll
    for (int rt = 0; rt < 2; ++rt)
      #pragma unroll
      for (int ct = 0; ct < 2; ++ct)
        #pragma unroll
        for (int r = 0; r < 4; ++r) {
          float s = st[rt][ct][r];
          u16 hi = f2b(s);
          float lo = s - b2f(hi);
          int row = rt * 16 + quad * 4 + r;
          int col = wv * 32 + ct * 16 + l16;
          Sh[row][col] = hi;
          Sl[row][col] = f2b(lo);
        }

    if (wv == 0) {
      float av = (lane < 32) ? abase[(size_t)(t0 + lane) * 16]
                             : bbase[(size_t)(t0 + lane - 32) * 16];
      float p = av;
      #pragma unroll
      for (int d = 1; d < 32; d <<= 1) {
        float up = __shfl_up(p, d);
        if (lane >= d && lane < 32) p *= up;
      }
      float pm1 = __shfl_up(p, 1);
      float bt = __shfl(av, lane + 32);
      if (lane < 32) {
        if (lane == 0) pm1 = 1.f;
        f32x4 g;
        g[0] = bt * pm1;       // s_t
        g[1] = bt;             // b_t
        g[2] = 1.0f / p;       // 1/P_t
        g[3] = p;              // P_t
        *(f32x4*)PL4[lane] = g;
      }
    } else {
      // staging: 1152 vec8 jobs over 192 threads (6 each): K 0..511, Q 512..1023, V 1024..1151
      u16x8 tmp[6];
      int jb = tid - 64;
      #pragma unroll
      for (int it = 0; it < 6; ++it) {
        int j = jb + it * 192;
        if (j < 512) {
          int t = j >> 4, g = j & 15;
          tmp[it] = *(const u16x8*)(kbase + (size_t)(t0 + t) * QKVC + g * 8);
        } else if (j < 1024) {
          int j2 = j - 512; int t = j2 >> 4, g = j2 & 15;
          tmp[it] = *(const u16x8*)(qbase + (size_t)(t0 + t) * QKVC + g * 8);
        } else {
          int j2 = j - 1024; int t = j2 >> 2, rg = j2 & 3;
          tmp[it] = *(const u16x8*)(vbase + (size_t)(t0 + t) * QKVC + rg * 8);
        }
      }
      #pragma unroll
      for (int it = 0; it < 6; ++it) {
        int j = jb + it * 192;
        if (j < 512) {
          int t = j >> 4, g = j & 15;
          *(u16x8*)&Kim[t][g * 8] = tmp[it];
          #pragma unroll
          for (int e = 0; e < 8; ++e) KT[g * 8 + e][t] = tmp[it][e];
        } else if (j < 1024) {
          int j2 = j - 512; int t = j2 >> 4, g = j2 & 15;
          *(u16x8*)&Qim[t][g * 8] = tmp[it];
        } else {
          int j2 = j - 1024; int t = j2 >> 2, rg = j2 & 3;
          *(u16x8*)&Vim[t][rg * 8] = tmp[it];
        }
      }
    }
    __syncthreads();

    // ---- ph2: KK, KQ, SK0, SQ0 (wave wv -> output tile (mt,nt)) ----
    {
      int mt = wv >> 1, nt = wv & 1;
      f32x4 aKK = {0.f,0.f,0.f,0.f}, aKQ = {0.f,0.f,0.f,0.f};
      f32x4 aSK = {0.f,0.f,0.f,0.f}, aSQ = {0.f,0.f,0.f,0.f};
      #pragma unroll
      for (int ks = 0; ks < 4; ++ks) {
        bf16x8 Ak  = *(const bf16x8*)&Kim[mt * 16 + l16][ks * 32 + quad * 8];
        bf16x8 Aq  = *(const bf16x8*)&Qim[mt * 16 + l16][ks * 32 + quad * 8];
        bf16x8 Bk  = *(const bf16x8*)&Kim[nt * 16 + l16][ks * 32 + quad * 8];
        bf16x8 Bsh = *(const bf16x8*)&Sh[nt * 16 + l16][ks * 32 + quad * 8];
        bf16x8 Bsl = *(const bf16x8*)&Sl[nt * 16 + l16][ks * 32 + quad * 8];
        aKK = MFMA16(Ak, Bk, aKK);
        aKQ = MFMA16(Aq, Bk, aKQ);
        aSK = MFMA16(Ak, Bsh, aSK);
        aSK = MFMA16(Ak, Bsl, aSK);
        aSQ = MFMA16(Aq, Bsh, aSQ);
        aSQ = MFMA16(Aq, Bsl, aSQ);
      }
      #pragma unroll
      for (int r = 0; r < 4; ++r) {
        int m = mt * 16 + quad * 4 + r, n = nt * 16 + l16;
        KK[m][n] = aKK[r]; KQ[m][n] = aKQ[r];
        SK0[m][n] = aSK[r]; SQ0[m][n] = aSQ[r];
      }
    }
    __syncthreads();

    // ---- ph3: triangular solve for u (wave0, lane = state row) ----
    if (wv == 0 && lane < 32) {
      float ub[C_];
      #pragma unroll
      for (int t = 0; t < C_; ++t) {
        f32x4 g = *(const f32x4*)PL4[t];          // uniform broadcast
        float u = g[0] * SK0[t][lane] - g[1] * b2f(Vim[t][lane]);
        float acc = 0.f;
        #pragma unroll
        for (int i = 0; i < t; ++i) acc = fmaf(KK[t][i], ub[i], acc);
        u = fmaf(-g[0], acc, u);
        U[t][lane] = u;
        ub[t] = g[2] * u;                          // ubar_t = u_t / P_t
      }
    }
    __syncthreads();

    // ---- ph4: build bf16 hi/lo images: Ut, Ucoef, G ----
    {
      float PL31 = PL4[31][3];
      int row = tid & 31, i0 = (tid >> 5) * 4;
      #pragma unroll
      for (int ii = 0; ii < 4; ++ii) {
        int i = i0 + ii;
        float rPi = PL4[i][2];
        float uv = U[i][row];
        u16 h1 = f2b(uv);
        Uth[row][i] = h1; Utl[row][i] = f2b(uv - b2f(h1));
        float ucv = -PL31 * rPi * uv;
        u16 h2 = f2b(ucv);
        Uch[row][i] = h2; Ucl[row][i] = f2b(ucv - b2f(h2));
        // G row index: t = row (thread-mapping reuse); store -P_t/P_i * KQ[t,i], i<=t
        float gv = (i <= row) ? (-PL4[row][3] * rPi * KQ[row][i]) : 0.f;
        u16 h3 = f2b(gv);
        Gh[row][i] = h3; Gl[row][i] = f2b(gv - b2f(h3));
      }
    }
    __syncthreads();

    // ---- ph5: state update + outputs ----
    {
      float PL31 = PL4[31][3];
      // state: S = P31*S + sum_i Ucoef[row,i] * KT[col,i]
      #pragma unroll
      for (int rt = 0; rt < 2; ++rt) {
        bf16x8 Ah = *(const bf16x8*)&Uch[rt * 16 + l16][quad * 8];
        bf16x8 Al = *(const bf16x8*)&Ucl[rt * 16 + l16][quad * 8];
        #pragma unroll
        for (int ct = 0; ct < 2; ++ct) {
          bf16x8 Bk = *(const bf16x8*)&KT[wv * 32 + ct * 16 + l16][quad * 8];
          f32x4 cacc;
          #pragma unroll
          for (int r = 0; r < 4; ++r) cacc[r] = PL31 * st[rt][ct][r];
          cacc = MFMA16(Ah, Bk, cacc);
          cacc = MFMA16(Al, Bk, cacc);
          st[rt][ct] = cacc;
        }
      }
      // outputs: o[t,row] = P_t*SQ0[t,row] + sum_i G[t,i]*u_i[row]   (minus folded into G)
      int mt = wv >> 1, nt = wv & 1;
      bf16x8 Agh = *(const bf16x8*)&Gh[mt * 16 + l16][quad * 8];
      bf16x8 Agl = *(const bf16x8*)&Gl[mt * 16 + l16][quad * 8];
      bf16x8 Buh = *(const bf16x8*)&Uth[nt * 16 + l16][quad * 8];
      bf16x8 Bul = *(const bf16x8*)&Utl[nt * 16 + l16][quad * 8];
      f32x4 oacc;
      #pragma unroll
      for (int r = 0; r < 4; ++r) {
        int t = mt * 16 + quad * 4 + r;
        oacc[r] = PL4[t][3] * SQ0[t][nt * 16 + l16];
      }
      oacc = MFMA16(Agh, Buh, oacc);
      oacc = MFMA16(Agh, Bul, oacc);
      oacc = MFMA16(Agl, Buh, oacc);
      #pragma unroll
      for (int r = 0; r < 4; ++r) {
        int t = mt * 16 + quad * 4 + r;
        obase[(size_t)(t0 + t) * 2048 + nt * 16 + l16] = f2b(oacc[r]);
      }
    }
    __syncthreads();
  }
}

// ---------------- LayerNorm(DV) * sigmoid(g) ----------------
__global__ __launch_bounds__(256) void ln_gate_k(const u16* __restrict__ o_raw,
                                                 const u16* __restrict__ g,
                                                 const u16* __restrict__ lnw,
                                                 const u16* __restrict__ lnb,
                                                 u16* __restrict__ o_ln)
{
  int gid = blockIdx.x * 4 + (threadIdx.x >> 6);
  int lane = threadIdx.x & 63;
  int row = gid >> 4, h = gid & 15;
  size_t ofs = (size_t)row * 2048 + h * 128 + lane * 2;
  unsigned int e2 = *(const unsigned int*)(o_raw + ofs);
  float ex = b2f((u16)(e2 & 0xffff)), ey = b2f((u16)(e2 >> 16));
  float s = ex + ey, ss = ex * ex + ey * ey;
  #pragma unroll
  for (int m = 1; m < 64; m <<= 1) { s += __shfl_xor(s, m); ss += __shfl_xor(ss, m); }
  float mean = s * (1.f / 128.f);
  float var  = ss * (1.f / 128.f) - mean * mean;
  float rstd = rsqrtf(fmaxf(var, 0.f) + 1e-5f);
  float w0 = b2f(lnw[lane * 2]), w1 = b2f(lnw[lane * 2 + 1]);
  float b0 = b2f(lnb[lane * 2]), b1 = b2f(lnb[lane * 2 + 1]);
  unsigned int g2 = *(const unsigned int*)(g + ofs);
  float g0 = sigm(b2f((u16)(g2 & 0xffff))), g1 = sigm(b2f((u16)(g2 >> 16)));
  float r0 = ((ex - mean) * rstd * w0 + b0) * g0;
  float r1 = ((ey - mean) * rstd * w1 + b1) * g1;
  *(unsigned int*)(o_ln + ofs) = (unsigned int)f2b(r0) | ((unsigned int)f2b(r1) << 16);
}

// ---------------- host launch ----------------
extern "C" void kernel_launch(void* const* d_in, const int* in_sizes, int n_in,
                              void* d_out, int out_size, void* d_ws, size_t ws_size,
                              hipStream_t stream)
{
  const float* x   = (const float*)d_in[0];
  const float* Wq  = (const float*)d_in[1];
  const float* Wk  = (const float*)d_in[2];
  const float* Wv  = (const float*)d_in[3];
  const float* Wa  = (const float*)d_in[4];
  const float* ba  = (const float*)d_in[5];
  const float* Wb  = (const float*)d_in[6];
  const float* bb  = (const float*)d_in[7];
  const float* Wg  = (const float*)d_in[8];
  const float* Wo  = (const float*)d_in[9];
  const float* qcw = (const float*)d_in[10];
  const float* qcb = (const float*)d_in[11];
  const float* kcw = (const float*)d_in[12];
  const float* kcb = (const float*)d_in[13];
  const float* vcw = (const float*)d_in[14];
  const float* vcb = (const float*)d_in[15];
  const float* lnw = (const float*)d_in[16];
  const float* lnb = (const float*)d_in[17];
  (void)in_sizes; (void)n_in; (void)out_size;

  char* ws = (char*)d_ws;
  size_t off = 0;
  auto alloc = [&](size_t bytes) -> void* {
    void* p = ws + off; off += (bytes + 255) & ~(size_t)255; return p;
  };
  u16* WT    = (u16*)alloc((size_t)3 * HID_ * HID_ * 2);
  u16* WabT  = (u16*)alloc((size_t)32 * HID_ * 2);
  u16* xc    = (u16*)alloc((size_t)BT_ * HID_ * 2);
  u16* canon = (u16*)alloc((size_t)31008 * 2);
  u16* preC  = (u16*)alloc((size_t)BT_ * HID_ * 2 * 2);
  u16* post  = (u16*)alloc((size_t)BT_ * QKVC * 2);
  float* abuf = (float*)alloc((size_t)2 * BT_ * 16 * 4);
  if (off > ws_size) return;

  u16* cw_c  = canon;
  u16* cb_c  = canon + 24576;
  u16* ba_c  = canon + 30720;
  u16* bb_c  = canon + 30736;
  u16* lnw_c = canon + 30752;
  u16* lnb_c = canon + 30880;

  u16* o_raw = preC;
  u16* g_raw = post;
  u16* o_ln  = post + (size_t)BT_ * HID_;
  u16* WTg   = WT;

  dim3 tb(256);

  cvt_x_k<<<dim3(4096), tb, 0, stream>>>((const f32x4*)x, (u16x4*)xc, BT_ * HID_ / 4);
  cvt_small_k<<<dim3(122), tb, 0, stream>>>(qcw, kcw, vcw, qcb, kcb, vcb, ba, bb, lnw, lnb, canon);

  transpose_b<<<dim3(64, 64, 3), tb, 0, stream>>>(Wq, Wk, Wv, WT, HID_, HID_);
  transpose_b<<<dim3(1, 64, 2), tb, 0, stream>>>(Wa, Wb, Wb, WabT, HID_, 16);

  for (int b = 0; b < B_; ++b) {
    const u16* xb = xc + (size_t)b * T_ * HID_;
    gemm_bt<<<dim3(QKVC / BN, T_ / BM), tb, 0, stream>>>(xb, HID_, WT, HID_, preC, QKVC, HID_, 0);
    conv_silu_k<<<dim3(T_ * (QKVC / 8) / 256), tb, 0, stream>>>(
        preC, cw_c, cb_c, post + (size_t)b * T_ * QKVC);
  }

  transpose_b<<<dim3(64, 64, 2), tb, 0, stream>>>(Wg, Wo, Wo, WTg, HID_, HID_);

  ab_k<<<dim3(BT_ / 8), tb, 0, stream>>>(xc, WabT, ba_c, bb_c, abuf);

  // chunked scan: 256 blocks = 4 row-slices x 64 chains
  chunk_scan_k<<<dim3(256), tb, 0, stream>>>(post, abuf, o_raw);

  gemm_bt<<<dim3(HID_ / BN, BT_ / BM), tb, 0, stream>>>(xc, HID_, WTg, HID_, g_raw, HID_, HID_, 0);

  ln_gate_k<<<dim3(BT_ * H_ / 4), tb, 0, stream>>>(o_raw, g_raw, lnw_c, lnb_c, o_ln);

  gemm_bt<<<dim3(HID_ / BN, BT_ / BM), tb, 0, stream>>>(o_ln, HID_,
      WT + (size_t)HID_ * HID_, HID_, d_out, HID_, HID_, 1);
}